// Round 1
// 271.847 us; speedup vs baseline: 1.0359x; 1.0359x over previous
//
#include <hip/hip_runtime.h>

#define NB   64
#define CIN  128
#define COUT 128
#define HH   64
#define WW   64
#define HW   4096

typedef float f4v __attribute__((ext_vector_type(4)));

// -------- workspace layout (float offsets) --------
// gapp : [N][8][128]  @ 0        per-(8-row-tile) per-channel sums
// xsmp : [N][8][4]    @ 65536    per-(8-row-tile, 16-col-block) channel-summed
// B    : [9][N][HW]   @ 73728    basis fields, j=0..7 -> W_i2 rows, j=8 -> b_i2
// coef : [N][160]     @ 2433024  [0:128)=co, [128:137)=sp, [137:145)=h_in

// K1: single pass over x. Block = (n, rt) 8-row tile; channel dim split across
// the two thread-halves. Weights transposed in LDS -> 3 broadcast DS reads/iter.
// In-loop reduction: 2 shuffles only; row reduction deferred to epilogue.
__global__ __launch_bounds__(256) void k_stats(const float* __restrict__ x,
                                               const float* __restrict__ W_i2,
                                               const float* __restrict__ b_i2,
                                               float* __restrict__ gapp,
                                               float* __restrict__ xsmp,
                                               float* __restrict__ B) {
    const int bid = blockIdx.x;        // n*8 + rt
    const int n  = bid >> 3;
    const int rt = bid & 7;
    const int tid = threadIdx.x;
    const int cs = tid >> 7;           // channel half (wave-uniform)
    const int p  = tid & 127;          // float4-pixel index in 8x64 tile
    const int row = p >> 4;            // 0..7
    const int colq = p & 15;           // float4 column
    const int wv = tid >> 6;           // wave 0..3
    const int lane = tid & 63;
    const int cb = colq >> 2;          // 16-col block

    __shared__ __align__(16) float lwt[2][64][12];  // [half][c][j] transposed
    __shared__ float bsw2[128][33];    // [channel][rep=(halfwave,row,cb)] partials
    __shared__ float cacc[9][4][128];  // half-1 accumulators for combine
    __shared__ float xw[4][4];         // [wave][cb] channel-summed partials

    for (int k = tid; k < 1152; k += 256) {
        const int half = k / 576;
        const int r = k - half * 576;
        const int c = r / 9;
        const int j = r - c * 9;
        lwt[half][c][j] = (j == 8) ? b_i2[half * 64 + c]
                                   : W_i2[j * CIN + half * 64 + c];
    }
    __syncthreads();

    float4 acc[9];
    #pragma unroll
    for (int j = 0; j < 9; ++j) acc[j] = make_float4(0.f, 0.f, 0.f, 0.f);
    float xacc = 0.0f;

    const size_t xbase = ((size_t)n * CIN + cs * 64) * HW
                       + (size_t)(rt * 8 + row) * WW + colq * 4;
    const int widx = ((wv & 1) << 4) | ((lane >> 4) << 2) | cb;  // 0..31
    const bool rep = (lane & 3) == 0;  // one lane per (row, cb)

    #pragma unroll 4
    for (int c = 0; c < 64; ++c) {
        f4v v = __builtin_nontemporal_load((const f4v*)(x + xbase + (size_t)c * HW));
        const float4 wa = *(const float4*)(&lwt[cs][c][0]);
        const float4 wb = *(const float4*)(&lwt[cs][c][4]);
        const float w8 = lwt[cs][c][8];
        const float wjs[9] = {wa.x, wa.y, wa.z, wa.w, wb.x, wb.y, wb.z, wb.w, w8};
        #pragma unroll
        for (int j = 0; j < 9; ++j) {
            acc[j].x += wjs[j] * v.x; acc[j].y += wjs[j] * v.y;
            acc[j].z += wjs[j] * v.z; acc[j].w += wjs[j] * v.w;
        }
        float ls = (v.x + v.y) + (v.z + v.w);
        xacc += ls;                    // xsm statistic: pure register accumulate
        ls += __shfl_xor(ls, 1, 64);
        ls += __shfl_xor(ls, 2, 64);
        if (rep) bsw2[cs * 64 + c][widx] = ls;   // 16-col row-segment sum
    }

    // xsm: reduce per-lane channel-summed value over colq (1,2) and rows (16,32)
    {
        float xs2 = xacc;
        xs2 += __shfl_xor(xs2, 1,  64);
        xs2 += __shfl_xor(xs2, 2,  64);
        xs2 += __shfl_xor(xs2, 16, 64);
        xs2 += __shfl_xor(xs2, 32, 64);
        if ((lane & 0x33) == 0) xw[wv][cb] = xs2;
    }
    __syncthreads();

    // half-1 parks its accumulators in LDS for the combine
    if (cs == 1) {
        #pragma unroll
        for (int j = 0; j < 9; ++j) {
            cacc[j][0][p] = acc[j].x; cacc[j][1][p] = acc[j].y;
            cacc[j][2][p] = acc[j].z; cacc[j][3][p] = acc[j].w;
        }
    }

    // gap partials: per-channel sum over this 8x64 tile (32 deferred partials)
    if (tid < 128) {
        float s = 0.0f;
        #pragma unroll
        for (int k = 0; k < 32; ++k) s += bsw2[tid][k];
        gapp[((size_t)n * 8 + rt) * 128 + tid] = s;
    }
    __syncthreads();

    if (tid < 4) {
        xsmp[((size_t)n * 8 + rt) * 4 + tid] =
            xw[0][tid] + xw[1][tid] + xw[2][tid] + xw[3][tid];
    }

    // half-0 combines and stores the 9 basis-field slices (coalesced)
    if (cs == 0) {
        const size_t bpix = (size_t)(rt * 8 + row) * WW + colq * 4;
        #pragma unroll
        for (int j = 0; j < 9; ++j) {
            f4v v2;
            v2.x = acc[j].x + cacc[j][0][p];
            v2.y = acc[j].y + cacc[j][1][p];
            v2.z = acc[j].z + cacc[j][2][p];
            v2.w = acc[j].w + cacc[j][3][p];
            __builtin_nontemporal_store(v2, (f4v*)(B + ((size_t)j * NB + n) * HW + bpix));
        }
    }
}

// K_coef: one block per sample; computes co[128], sp[9], h_in[8] once.
__global__ __launch_bounds__(128) void k_coef(
    const float* __restrict__ gapp, const float* __restrict__ xsmp,
    const float* __restrict__ W_sp, const float* __restrict__ b_sp,
    const float* __restrict__ W_o1, const float* __restrict__ b_o1,
    const float* __restrict__ W_o2, const float* __restrict__ b_o2,
    const float* __restrict__ W_i1, const float* __restrict__ b_i1,
    float* __restrict__ coef)
{
    const int n = blockIdx.x;
    const int tid = threadIdx.x;
    __shared__ float lgap[128];
    __shared__ float lxsm[16];
    __shared__ float lh[16];           // [0..7] out-hidden, [8..15] in-hidden

    {
        float s = 0.0f;
        #pragma unroll
        for (int rtv = 0; rtv < 8; ++rtv)
            s += gapp[((size_t)n * 8 + rtv) * 128 + tid];
        lgap[tid] = s * (1.0f / 4096.0f);
    }
    if (tid < 16) {
        const int rb = tid >> 2, cbk = tid & 3;
        const float s = xsmp[((size_t)n * 8 + rb * 2) * 4 + cbk]
                      + xsmp[((size_t)n * 8 + rb * 2 + 1) * 4 + cbk];
        lxsm[tid] = s * (1.0f / 32768.0f);
    }
    __syncthreads();

    // hidden layers: wave0 -> W_o1, wave1 -> W_i1; 8 lanes per hidden unit
    {
        const int wvv = tid >> 6, lane = tid & 63;
        const int j = lane >> 3, ch = lane & 7;
        const float* Wm = wvv ? W_i1 : W_o1;
        const float* bm = wvv ? b_i1 : b_o1;
        float a = 0.0f;
        #pragma unroll
        for (int i = 0; i < 16; ++i)
            a += lgap[ch * 16 + i] * Wm[(ch * 16 + i) * 8 + j];
        a += __shfl_xor(a, 1, 64);
        a += __shfl_xor(a, 2, 64);
        a += __shfl_xor(a, 4, 64);
        if (ch == 0) lh[wvv * 8 + j] = fmaxf(a + bm[j], 0.0f);
    }
    __syncthreads();

    float* cf = coef + (size_t)n * 160;
    {
        float acco = b_o2[tid];
        #pragma unroll
        for (int jj = 0; jj < 8; ++jj) acco += lh[jj] * W_o2[jj * 128 + tid];
        cf[tid] = acco;
    }
    if (tid < 9) {
        float a = b_sp[tid];
        #pragma unroll
        for (int jj = 0; jj < 16; ++jj) a += lxsm[jj] * W_sp[jj * 9 + tid];
        cf[128 + tid] = a;
    }
    if (tid < 8) cf[137 + tid] = lh[8 + tid];
}

// K2: load coefs, build t-tile (+halo, zero-padded borders), 3x3 stencil,
// scale by co[o], nontemporal store.
__global__ __launch_bounds__(256) void k_out(const float* __restrict__ B,
                                             const float* __restrict__ coef,
                                             float* __restrict__ out)
{
    const int bid = blockIdx.x;          // n*8 + ytile
    const int n  = bid >> 3;
    const int y0 = (bid & 7) * 8;
    const int tid = threadIdx.x;

    __shared__ float lh[8];
    __shared__ float lco[128];
    __shared__ float lsp[9];
    __shared__ float ts[10][67];         // cols 0 and 65 are zero borders; data at +1

    const float* cf = coef + (size_t)n * 160;
    if (tid < 128)       lco[tid]       = cf[tid];
    else if (tid < 137)  lsp[tid - 128] = cf[tid];
    else if (tid < 145)  lh[tid - 137]  = cf[tid];
    if (tid >= 160 && tid < 180) {
        const int r = (tid - 160) >> 1;
        ts[r][((tid - 160) & 1) * 65] = 0.0f;
    }
    __syncthreads();

    // ---- build rows y0-1 .. y0+8 of t (160 float4s) from 9 basis fields ----
    if (tid < 160) {
        const int ry = tid >> 4, cq = tid & 15;
        const int gy = y0 - 1 + ry;
        float4 tv = make_float4(0.f, 0.f, 0.f, 0.f);
        if (gy >= 0 && gy < HH) {
            const float* Bn = B + (size_t)n * HW + (size_t)gy * WW + cq * 4;
            tv = *(const float4*)(Bn + (size_t)8 * NB * HW);
            #pragma unroll
            for (int j = 0; j < 8; ++j) {
                const float h = lh[j];
                float4 u = *(const float4*)(Bn + (size_t)j * NB * HW);
                tv.x += h * u.x; tv.y += h * u.y;
                tv.z += h * u.z; tv.w += h * u.w;
            }
        }
        ts[ry][cq * 4 + 1] = tv.x; ts[ry][cq * 4 + 2] = tv.y;
        ts[ry][cq * 4 + 3] = tv.z; ts[ry][cq * 4 + 4] = tv.w;
    }
    __syncthreads();

    const int i = tid & 127;             // float4 index in 8x64 tile
    const int row = i >> 4;
    const int cc0 = (i & 15) * 4;
    float sv[4];
    #pragma unroll
    for (int u = 0; u < 4; ++u) {
        float a2 = 0.0f;
        #pragma unroll
        for (int dy = 0; dy < 3; ++dy) {
            #pragma unroll
            for (int dx = 0; dx < 3; ++dx)
                a2 += lsp[dy * 3 + dx] * ts[row + dy][cc0 + u + dx];
        }
        sv[u] = a2;
    }

    const int ohalf = (tid >> 7) * 64;
    float* outp = out + (size_t)n * COUT * HW + (size_t)y0 * WW + (size_t)i * 4;
    #pragma unroll 4
    for (int op = 0; op < 64; ++op) {
        const int o = ohalf + op;
        const float scl = lco[o];
        f4v v; v.x = sv[0] * scl; v.y = sv[1] * scl; v.z = sv[2] * scl; v.w = sv[3] * scl;
        __builtin_nontemporal_store(v, (f4v*)(outp + (size_t)o * HW));
    }
}

extern "C" void kernel_launch(void* const* d_in, const int* in_sizes, int n_in,
                              void* d_out, int out_size, void* d_ws, size_t ws_size,
                              hipStream_t stream) {
    const float* x    = (const float*)d_in[0];
    const float* W_sp = (const float*)d_in[1];
    const float* b_sp = (const float*)d_in[2];
    const float* W_o1 = (const float*)d_in[3];
    const float* b_o1 = (const float*)d_in[4];
    const float* W_o2 = (const float*)d_in[5];
    const float* b_o2 = (const float*)d_in[6];
    const float* W_i1 = (const float*)d_in[7];
    const float* b_i1 = (const float*)d_in[8];
    const float* W_i2 = (const float*)d_in[9];
    const float* b_i2 = (const float*)d_in[10];

    float* ws = (float*)d_ws;
    float* gapp = ws;
    float* xsmp = ws + 65536;
    float* B    = ws + 73728;
    float* coef = ws + 2433024;
    float* out  = (float*)d_out;

    k_stats<<<NB * 8, 256, 0, stream>>>(x, W_i2, b_i2, gapp, xsmp, B);
    k_coef<<<NB, 128, 0, stream>>>(gapp, xsmp, W_sp, b_sp, W_o1, b_o1,
                                   W_o2, b_o2, W_i1, b_i1, coef);
    k_out<<<NB * 8, 256, 0, stream>>>(B, coef, out);
}